// Round 5
// baseline (91.511 us; speedup 1.0000x reference)
//
#include <hip/hip_runtime.h>
#include <math.h>

#define N_RAYS   262144
#define HIDDEN   256
#define NEAR_T   1.0f
#define FAR_T    10.0f
#define MAX_IT   64

// ---------------------------------------------------------------------------
// Kernel 1: sphere trace only. RPT=1, 1024 blocks -> 4 waves/SIMD (TLP hides
// the serial sqrt chain). Writes float4{px,py,pz,hitflag} to ws (coalesced).
// Scalar form: f(t) = sqrt((t+B)^2 + C) - rad, same numerics as prior rounds.
// ---------------------------------------------------------------------------
__global__ __launch_bounds__(256)
void st_trace(const float* __restrict__ org,
              const float* __restrict__ dir,
              const float* __restrict__ center,
              const float* __restrict__ radius,
              float4* __restrict__ ws_p) {
    const int r = blockIdx.x * blockDim.x + threadIdx.x;

    const float cx = center[0], cy = center[1], cz = center[2];
    const float rad = radius[0];

    const float ox = org[3*r+0], oy = org[3*r+1], oz = org[3*r+2];
    const float dx = dir[3*r+0], dy = dir[3*r+1], dz = dir[3*r+2];

    const float qx = ox - cx, qy = oy - cy, qz = oz - cz;
    const float B  = qx*dx + qy*dy + qz*dz;
    const float ex = __builtin_fmaf(-B, dx, qx);
    const float ey = __builtin_fmaf(-B, dy, qy);
    const float ez = __builtin_fmaf(-B, dz, qz);
    const float C  = ex*ex + ey*ey + ez*ez;

    float u = NEAR_T + B;
    #pragma unroll
    for (int i = 0; i < MAX_IT; ++i) {
        const float f = __builtin_amdgcn_sqrtf(__builtin_fmaf(u, u, C)) - rad;
        u += f;
    }
    const float t   = u - B;
    const float hit = (t <= FAR_T) ? 1.0f : 0.0f;

    ws_p[r] = make_float4(__builtin_fmaf(t, dx, ox),
                          __builtin_fmaf(t, dy, oy),
                          __builtin_fmaf(t, dz, oz),
                          hit);
}

// ---------------------------------------------------------------------------
// Kernel 2: MLP. RPT=4 (minimum LDS-pipe cost), 256 blocks of 256.
// Weights in 7 SoA float4 LDS arrays; jq-group register prefetch pipeline
// hides LDS latency at 1 wave/SIMD. p loads are coalesced float4.
// ---------------------------------------------------------------------------
#define RPT   4
#define JQ    (HIDDEN / 4)

__global__ __launch_bounds__(256)
void st_mlp(const float4* __restrict__ ws_p,
            const float* __restrict__ w1,
            const float* __restrict__ b1,
            const float* __restrict__ w2,
            const float* __restrict__ b2,
            float* __restrict__ out) {
    __shared__ float4 s_wx[JQ], s_wy[JQ], s_wz[JQ], s_wb[JQ];
    __shared__ float4 s_wa[JQ], s_wv[JQ], s_wc[JQ];

    {
        const int j = threadIdx.x;            // BLOCK == HIDDEN
        ((float*)s_wx)[j] = w1[0*HIDDEN + j];
        ((float*)s_wy)[j] = w1[1*HIDDEN + j];
        ((float*)s_wz)[j] = w1[2*HIDDEN + j];
        ((float*)s_wb)[j] = b1[j];
        ((float*)s_wa)[j] = w2[3*j+0];
        ((float*)s_wv)[j] = w2[3*j+1];
        ((float*)s_wc)[j] = w2[3*j+2];
    }
    __syncthreads();

    const int base = blockIdx.x * (256 * RPT) + threadIdx.x;

    float px[RPT], py[RPT], pz[RPT], hf[RPT];
    #pragma unroll
    for (int k = 0; k < RPT; ++k) {
        const float4 p = ws_p[base + k * 256];
        px[k] = p.x; py[k] = p.y; pz[k] = p.z; hf[k] = p.w;
    }

    const float bb0 = b2[0], bb1 = b2[1], bb2 = b2[2];
    float a0[RPT], a1[RPT], a2[RPT];
    #pragma unroll
    for (int k = 0; k < RPT; ++k) { a0[k]=bb0; a1[k]=bb1; a2[k]=bb2; }

    // software-pipelined jq loop: prefetch next group while computing current
    float4 cwx = s_wx[0], cwy = s_wy[0], cwz = s_wz[0], cwb = s_wb[0];
    float4 cwa = s_wa[0], cwv = s_wv[0], cwc = s_wc[0];

    #pragma unroll 4
    for (int jq = 0; jq < JQ; ++jq) {
        float4 nwx, nwy, nwz, nwb, nwa, nwv, nwc;
        if (jq + 1 < JQ) {
            nwx = s_wx[jq+1]; nwy = s_wy[jq+1]; nwz = s_wz[jq+1]; nwb = s_wb[jq+1];
            nwa = s_wa[jq+1]; nwv = s_wv[jq+1]; nwc = s_wc[jq+1];
        }
        #pragma unroll
        for (int k = 0; k < RPT; ++k) {
            float h;
            h = __builtin_fmaf(px[k], cwx.x, __builtin_fmaf(py[k], cwy.x,
                __builtin_fmaf(pz[k], cwz.x, cwb.x)));
            h = fmaxf(h, 0.0f);
            a0[k] = __builtin_fmaf(h, cwa.x, a0[k]);
            a1[k] = __builtin_fmaf(h, cwv.x, a1[k]);
            a2[k] = __builtin_fmaf(h, cwc.x, a2[k]);

            h = __builtin_fmaf(px[k], cwx.y, __builtin_fmaf(py[k], cwy.y,
                __builtin_fmaf(pz[k], cwz.y, cwb.y)));
            h = fmaxf(h, 0.0f);
            a0[k] = __builtin_fmaf(h, cwa.y, a0[k]);
            a1[k] = __builtin_fmaf(h, cwv.y, a1[k]);
            a2[k] = __builtin_fmaf(h, cwc.y, a2[k]);

            h = __builtin_fmaf(px[k], cwx.z, __builtin_fmaf(py[k], cwy.z,
                __builtin_fmaf(pz[k], cwz.z, cwb.z)));
            h = fmaxf(h, 0.0f);
            a0[k] = __builtin_fmaf(h, cwa.z, a0[k]);
            a1[k] = __builtin_fmaf(h, cwv.z, a1[k]);
            a2[k] = __builtin_fmaf(h, cwc.z, a2[k]);

            h = __builtin_fmaf(px[k], cwx.w, __builtin_fmaf(py[k], cwy.w,
                __builtin_fmaf(pz[k], cwz.w, cwb.w)));
            h = fmaxf(h, 0.0f);
            a0[k] = __builtin_fmaf(h, cwa.w, a0[k]);
            a1[k] = __builtin_fmaf(h, cwv.w, a1[k]);
            a2[k] = __builtin_fmaf(h, cwc.w, a2[k]);
        }
        cwx = nwx; cwy = nwy; cwz = nwz; cwb = nwb;
        cwa = nwa; cwv = nwv; cwc = nwc;
    }

    #pragma unroll
    for (int k = 0; k < RPT; ++k) {
        const int r = base + k * 256;
        const bool hit = (hf[k] != 0.0f);
        const float s0 = 1.0f / (1.0f + __expf(-a0[k]));
        const float s1 = 1.0f / (1.0f + __expf(-a1[k]));
        const float s2 = 1.0f / (1.0f + __expf(-a2[k]));
        out[3*r+0] = hit ? s0 : 0.0f;
        out[3*r+1] = hit ? s1 : 0.0f;
        out[3*r+2] = hit ? s2 : 0.0f;
    }
}

// ---------------------------------------------------------------------------
extern "C" void kernel_launch(void* const* d_in, const int* in_sizes, int n_in,
                              void* d_out, int out_size, void* d_ws, size_t ws_size,
                              hipStream_t stream) {
    const float* org    = (const float*)d_in[0];
    const float* dir    = (const float*)d_in[1];
    const float* center = (const float*)d_in[2];
    const float* radius = (const float*)d_in[3];
    const float* w1     = (const float*)d_in[4];
    const float* b1     = (const float*)d_in[5];
    const float* w2     = (const float*)d_in[6];
    const float* b2     = (const float*)d_in[7];
    float* out = (float*)d_out;

    float4* ws_p = (float4*)d_ws;    // 262144 * 16 B = 4 MB scratch

    st_trace<<<N_RAYS / 256, 256, 0, stream>>>(org, dir, center, radius, ws_p);
    st_mlp<<<N_RAYS / (256 * RPT), 256, 0, stream>>>(ws_p, w1, b1, w2, b2, out);
}

// Round 6
// 89.208 us; speedup vs baseline: 1.0258x; 1.0258x over previous
//
#include <hip/hip_runtime.h>
#include <math.h>

#define N_RAYS   262144
#define HIDDEN   256
#define NEAR_T   1.0f
#define FAR_T    10.0f
#define MAX_IT   64

// Single fused kernel, RPT=1 (1024 blocks -> 4 waves/SIMD).
// Key change vs rounds 1-5: NO LDS at all. All MLP weight accesses are
// wave-uniform with compile-time indices (full unroll) -> compiler emits
// s_load through the constant cache; weights live in SGPRs and embed
// directly as VOP3 operands. VALU does only the 7 FMA-class ops per hidden
// unit; the LDS pipe (the ~40us invariant of rounds 1-5) is idle.
__global__ __launch_bounds__(256)
void st_fused_sgpr(const float* __restrict__ org,
                   const float* __restrict__ dir,
                   const float* __restrict__ center,
                   const float* __restrict__ radius,
                   const float* __restrict__ w1,
                   const float* __restrict__ b1,
                   const float* __restrict__ w2,
                   const float* __restrict__ b2,
                   float* __restrict__ out) {
    const int r = blockIdx.x * blockDim.x + threadIdx.x;

    const float cx = center[0], cy = center[1], cz = center[2];
    const float rad = radius[0];

    const float ox = org[3*r+0], oy = org[3*r+1], oz = org[3*r+2];
    const float dx = dir[3*r+0], dy = dir[3*r+1], dz = dir[3*r+2];

    // q = o - c;  B = q.d;  C = |q - B d|^2   (cancellation-free perp dist^2)
    const float qx = ox - cx, qy = oy - cy, qz = oz - cz;
    const float B  = qx*dx + qy*dy + qz*dz;
    const float ex = __builtin_fmaf(-B, dx, qx);
    const float ey = __builtin_fmaf(-B, dy, qy);
    const float ez = __builtin_fmaf(-B, dz, qz);
    const float C  = ex*ex + ey*ey + ez*ez;

    // u = t + B;  f(t) = sqrt(u^2 + C) - rad;  u monotone increasing.
    float u = NEAR_T + B;
    #pragma unroll
    for (int i = 0; i < MAX_IT; ++i) {
        u += __builtin_amdgcn_sqrtf(__builtin_fmaf(u, u, C)) - rad;
    }
    const float t   = u - B;
    const bool  hit = (t <= FAR_T);

    const float px = __builtin_fmaf(t, dx, ox);
    const float py = __builtin_fmaf(t, dy, oy);
    const float pz = __builtin_fmaf(t, dz, oz);

    // MLP: h = relu(p @ w1 + b1); rgb = sigmoid(h @ w2 + b2)
    // Fully unrolled -> every weight index is a literal -> uniform address ->
    // scalar loads (constant cache), SGPR operands in the FMAs.
    float a0 = b2[0], a1 = b2[1], a2 = b2[2];
    #pragma unroll
    for (int j = 0; j < HIDDEN; ++j) {
        float h = __builtin_fmaf(px, w1[0*HIDDEN + j],
                  __builtin_fmaf(py, w1[1*HIDDEN + j],
                  __builtin_fmaf(pz, w1[2*HIDDEN + j], b1[j])));
        h = fmaxf(h, 0.0f);
        a0 = __builtin_fmaf(h, w2[3*j+0], a0);
        a1 = __builtin_fmaf(h, w2[3*j+1], a1);
        a2 = __builtin_fmaf(h, w2[3*j+2], a2);
    }

    const float s0 = 1.0f / (1.0f + __expf(-a0));
    const float s1 = 1.0f / (1.0f + __expf(-a1));
    const float s2 = 1.0f / (1.0f + __expf(-a2));

    out[3*r+0] = hit ? s0 : 0.0f;
    out[3*r+1] = hit ? s1 : 0.0f;
    out[3*r+2] = hit ? s2 : 0.0f;
}

extern "C" void kernel_launch(void* const* d_in, const int* in_sizes, int n_in,
                              void* d_out, int out_size, void* d_ws, size_t ws_size,
                              hipStream_t stream) {
    const float* org    = (const float*)d_in[0];
    const float* dir    = (const float*)d_in[1];
    const float* center = (const float*)d_in[2];
    const float* radius = (const float*)d_in[3];
    const float* w1     = (const float*)d_in[4];
    const float* b1     = (const float*)d_in[5];
    const float* w2     = (const float*)d_in[6];
    const float* b2     = (const float*)d_in[7];
    float* out = (float*)d_out;

    st_fused_sgpr<<<N_RAYS / 256, 256, 0, stream>>>(org, dir, center, radius,
                                                    w1, b1, w2, b2, out);
}